// Round 12
// baseline (2989.152 us; speedup 1.0000x reference)
//
#include <hip/hip_runtime.h>

#define BB 32
#define QQ 16384
#define GG 128
#define KK 32
#define NN 9
#define CELLS 16
#define NCELL (CELLS * CELLS)
#define CAP 192    // per-wave candidate capacity (expected ~36)
#define MAXR 18    // rows <= 16 (+ sentinel)
#define MTH 512    // main kernel: 8 waves/block, 1 wave per GT

typedef unsigned long long u64;
typedef unsigned int u32;

#define INFF __uint_as_float(0x7F800000u)

// packed ascending key: (float bits of nonneg key) << 32 | idx
// lexicographic u64 compare == (value asc, index asc) == jax top_k tie rule
__device__ __forceinline__ u64 pack_asc(float key, u32 idx) {
  return (((u64)__float_as_uint(key)) << 32) | (u64)idx;
}

// EXACT reference squared distance: ((dx^2+dy^2)+dz^2)+dw^2, no contraction.
// ref d = sqrtf(this).
__device__ __forceinline__ float dist2_ref(const float4 g, const float4 p) {
#pragma clang fp contract(off)
  float dx = g.x - p.x;
  float dy = g.y - p.y;
  float dz = g.z - p.z;
  float dw = g.w - p.w;
  float s = dx * dx + dy * dy;
  s = s + dz * dz;
  s = s + dw * dw;
  return s;
}

// IoU exactly as reference (cxcywh -> xyxy, clip, same op order)
__device__ __forceinline__ float iou_ref(const float4 g, const float4 p) {
#pragma clang fp contract(off)
  float gx1 = g.x - 0.5f * g.z, gy1 = g.y - 0.5f * g.w;
  float gx2 = g.x + 0.5f * g.z, gy2 = g.y + 0.5f * g.w;
  float px1 = p.x - 0.5f * p.z, py1 = p.y - 0.5f * p.w;
  float px2 = p.x + 0.5f * p.z, py2 = p.y + 0.5f * p.w;
  float ltx = fmaxf(gx1, px1), lty = fmaxf(gy1, py1);
  float rbx = fminf(gx2, px2), rby = fminf(gy2, py2);
  float wx = fmaxf(rbx - ltx, 0.0f), wy = fmaxf(rby - lty, 0.0f);
  float inter = wx * wy;
  float aa = (gx2 - gx1) * (gy2 - gy1);
  float ab = (px2 - px1) * (py2 - py1);
  return inter / ((aa + ab) - inter);
}

// full ascending bitonic sort across one 64-lane wave, u64 keys
__device__ __forceinline__ u64 bitonic64(u64 v, int lane) {
#pragma unroll
  for (int k = 2; k <= 64; k <<= 1) {
#pragma unroll
    for (int j = k >> 1; j > 0; j >>= 1) {
      u64 o = __shfl_xor(v, j, 64);
      bool up = ((lane & k) == 0);
      bool lower = ((lane & j) == 0);
      v = (lower == up) ? (v < o ? v : o) : (v > o ? v : o);
    }
  }
  return v;
}

// full ascending bitonic sort across one 64-lane wave, float keys
__device__ __forceinline__ float bitonic64f(float v, int lane) {
#pragma unroll
  for (int k = 2; k <= 64; k <<= 1) {
#pragma unroll
    for (int j = k >> 1; j > 0; j >>= 1) {
      float o = __shfl_xor(v, j, 64);
      bool up = ((lane & k) == 0);
      bool lower = ((lane & j) == 0);
      v = (lower == up) ? fminf(v, o) : fmaxf(v, o);
    }
  }
  return v;
}

// ==================== kernel 1: bin preds by (cx,cy) cell ====================
__global__ __launch_bounds__(1024) void bin_kernel(
    const float4* __restrict__ pred, float4* __restrict__ S,
    unsigned short* __restrict__ I, int* __restrict__ cellStart) {
  __shared__ int cnt[NCELL];
  __shared__ int off[NCELL];
  const int t = threadIdx.x;
  const int b = blockIdx.x;
  if (t < NCELL) cnt[t] = 0;
  __syncthreads();
  const float4* pb = pred + (size_t)b * QQ;
  int cells[QQ / 1024];
#pragma unroll
  for (int j = 0; j < QQ / 1024; ++j) {
    float4 p = pb[t + j * 1024];
    int cx = min(CELLS - 1, max(0, (int)(p.x * CELLS)));
    int cy = min(CELLS - 1, max(0, (int)(p.y * CELLS)));
    int c = cy * CELLS + cx;
    cells[j] = c;
    atomicAdd(&cnt[c], 1);
  }
  __syncthreads();
  if (t == 0) {
    int acc = 0;
    for (int c = 0; c < NCELL; ++c) {
      off[c] = acc;
      acc += cnt[c];
    }
  }
  __syncthreads();
  if (t < NCELL) cellStart[b * (NCELL + 1) + t] = off[t];
  if (t == 0) cellStart[b * (NCELL + 1) + NCELL] = QQ;
  __syncthreads();  // snapshot off before scatter mutates it
#pragma unroll
  for (int j = 0; j < QQ / 1024; ++j) {
    int i = t + j * 1024;
    float4 p = pb[i];
    int pos = atomicAdd(&off[cells[j]], 1);
    S[(size_t)b * QQ + pos] = p;
    I[(size_t)b * QQ + pos] = (unsigned short)i;
  }
}

// ==================== kernel 2: one wave per GT ====================
__global__ __launch_bounds__(MTH) void assign_kernel(
    const float4* __restrict__ pred, const float4* __restrict__ gtb,
    const float4* __restrict__ S, const unsigned short* __restrict__ I,
    const int* __restrict__ cellStart, int* __restrict__ out) {
  __shared__ float ckey[MTH / 64][CAP];
  __shared__ unsigned short cidx[MTH / 64][CAP];
  __shared__ int rowS[MTH / 64][MAXR];
  __shared__ int rowC[MTH / 64][MAXR + 1];
  __shared__ int kidx[MTH / 64][KK];
  __shared__ int nC[MTH / 64];

  const int t = threadIdx.x;
  const int w = t >> 6, lane = t & 63;
  // XCD swizzle: the 16 blocks of one batch share an XCD -> S_b slice in L2
  const int blk = blockIdx.x;
  const int b = (blk & 7) * 4 + (blk >> 7);
  const int g = ((blk >> 3) & 15) * (MTH / 64) + w;
  const int task = b * GG + g;
  if (lane == 0) nC[w] = 0;

  const float4 gt = gtb[task];
  const float4* Sb = S + (size_t)b * QQ;
  const unsigned short* Ib = I + (size_t)b * QQ;
  const int* cs = cellStart + b * (NCELL + 1);
  const float4* pb = pred + (size_t)b * QQ;

  const int cgx = min(CELLS - 1, max(0, (int)(gt.x * CELLS)));
  const int cgy = min(CELLS - 1, max(0, (int)(gt.y * CELLS)));

  // ---- phase A rows: expand square ring until >=128 points (rows only) ----
  int cnt = 0, nR = 0;
  for (int r = 1; r <= CELLS; ++r) {
    int y0 = max(0, cgy - r), y1 = min(CELLS - 1, cgy + r);
    int x0 = max(0, cgx - r), x1 = min(CELLS - 1, cgx + r);
    nR = y1 - y0 + 1;
    int len = 0, st = 0;
    if (lane < nR) {
      int y = y0 + lane;
      st = cs[y * CELLS + x0];
      len = cs[y * CELLS + x1 + 1] - st;
    }
    int incl = len;
#pragma unroll
    for (int d = 1; d < 64; d <<= 1) {
      int o = __shfl_up(incl, d, 64);
      if (lane >= d) incl += o;
    }
    cnt = __shfl(incl, nR - 1, 64);
    if (lane < nR) {
      rowS[w][lane] = st;
      rowC[w][lane] = incl - len;
    }
    if (lane == nR) rowC[w][nR] = incl;  // == cnt (len 0 for lane >= nR)
    if (cnt >= 128 || r == CELLS) break;
  }

  // ---- phase A scan: exact d2, per-lane 2 smallest (disjoint flattened
  // assignment: lane l owns global positions == l mod 64; cnt>=128 ->
  // every lane >= 2 elements -> 128 kept values from distinct elements).
  float m1 = INFF, m2 = INFF;
  {
    int ri = 0;
    for (int gq = lane; gq < cnt; gq += 64) {
      while (gq >= rowC[w][ri + 1]) ++ri;
      int e = rowS[w][ri] + (gq - rowC[w][ri]);
      float d2 = dist2_ref(gt, Sb[e]);
      float nm1 = fminf(m1, d2);
      m2 = fminf(m2, fmaxf(m1, d2));
      m1 = nm1;
    }
  }

  // ---- U2 = 32nd smallest of the 128 kept exact d2 values ----
  // >=32 distinct elements have d2 <= U2, so U2 >= true 32nd-smallest d2.
  float A = bitonic64f(m1, lane);
  float Bs = bitonic64f(m2, lane);
  float Br = __shfl(Bs, 63 - lane, 64);
  float m = fminf(A, Br);  // bitonic, holds the 64 smallest
#pragma unroll
  for (int j = 32; j > 0; j >>= 1) {
    float o = __shfl_xor(m, j, 64);
    m = ((lane & j) == 0) ? fminf(m, o) : fmaxf(m, o);
  }
  float U2 = __shfl(m, 31, 64);
  // only sqrt-collapse margin needed (all arithmetic is exact ref-form):
  const float T = U2 * 1.00002f + 4e-6f;

  // ---- phase B rows: all cells intersecting the 2D disk of radius
  // sqrt(T) around (gt.x, gt.y). d2<=T => dcx^2+dcy^2<=T => point's cell
  // is in this set (1e-4 margins crush any float/binning slop; margins
  // only ADD cells -> conservative).
  float radT = sqrtf(T) + 1e-4f;
  int yLo = max(0, (int)floorf((gt.y - radT) * CELLS));
  int yHi = min(CELLS - 1, (int)floorf((gt.y + radT) * CELLS));
  int nR2 = yHi - yLo + 1;
  int cnt2;
  {
    int len = 0, st = 0;
    if (lane < nR2) {
      int y = yLo + lane;
      float ylo = (float)y / CELLS, yhi = (float)(y + 1) / CELLS;
      float dy = fmaxf(0.0f, fmaxf(ylo - gt.y, gt.y - yhi));
      dy = fmaxf(0.0f, dy - 1e-4f);
      float rem = T - dy * dy;
      if (rem >= 0.0f) {
        float dx = sqrtf(rem) + 1e-4f;
        int x0 = max(0, (int)floorf((gt.x - dx) * CELLS));
        int x1 = min(CELLS - 1, (int)floorf((gt.x + dx) * CELLS));
        st = cs[y * CELLS + x0];
        len = cs[y * CELLS + x1 + 1] - st;
      }
    }
    int incl = len;
#pragma unroll
    for (int d = 1; d < 64; d <<= 1) {
      int o = __shfl_up(incl, d, 64);
      if (lane >= d) incl += o;
    }
    cnt2 = __shfl(incl, nR2 - 1, 64);
    if (lane < nR2) {
      rowS[w][lane] = st;
      rowC[w][lane] = incl - len;
    }
    if (lane == nR2) rowC[w][nR2] = incl;
  }

  // ---- phase B scan: collect exact-d2 candidates (orig idx from Ib) ----
  {
    int ri = 0;
    for (int gq = lane; gq < cnt2; gq += 64) {
      while (gq >= rowC[w][ri + 1]) ++ri;
      int e = rowS[w][ri] + (gq - rowC[w][ri]);
      float d2 = dist2_ref(gt, Sb[e]);
      if (d2 <= T) {
        int pos = atomicAdd(&nC[w], 1);
        if (pos < CAP) {
          ckey[w][pos] = d2;
          cidx[w][pos] = Ib[e];
        }
      }
    }
  }
  int n = nC[w];  // >= 32: every ref-top-32 point has d2 <= U2 <= T

  // ---- select top-32 by (d, idx) ascending; d = sqrtf(d2) (IEEE == jnp)
  if (n > CAP) {
    // pathological-only exact serial fallback over original pred
    if (lane == 0) {
      u64 best[KK];
      for (int l = 0; l < KK; ++l) best[l] = ~0ull;
      for (int i = 0; i < QQ; ++i) {
        float d = sqrtf(dist2_ref(gt, pb[i]));
        u64 pk = pack_asc(d, (u32)i);
        if (pk < best[KK - 1]) {
          int pos = KK - 1;
          while (pos > 0 && best[pos - 1] > pk) {
            best[pos] = best[pos - 1];
            --pos;
          }
          best[pos] = pk;
        }
      }
      for (int l = 0; l < KK; ++l) kidx[w][l] = (int)(best[l] & 0xFFFFFFFFull);
    }
  } else if (n <= 64) {
    // fast path (expected ~100%)
    u64 v = (lane < n) ? pack_asc(sqrtf(ckey[w][lane]), (u32)cidx[w][lane])
                       : ~0ull;
    u64 s = bitonic64(v, lane);
    if (lane < KK) kidx[w][lane] = (int)(s & 0xFFFFFFFFull);
  } else if (n <= 128) {
    // two-register bitonic merge: smallest 64 of <=128, sorted
    u64 v1 = (lane < n) ? pack_asc(sqrtf(ckey[w][lane]), (u32)cidx[w][lane])
                        : ~0ull;
    u64 v2 = (64 + lane < n)
                 ? pack_asc(sqrtf(ckey[w][64 + lane]), (u32)cidx[w][64 + lane])
                 : ~0ull;
    u64 s1 = bitonic64(v1, lane);
    u64 s2 = bitonic64(v2, lane);
    u64 s2r = __shfl(s2, 63 - lane, 64);
    u64 lo = s1 < s2r ? s1 : s2r;  // bitonic, holds the 64 smallest
#pragma unroll
    for (int j = 32; j > 0; j >>= 1) {
      u64 o = __shfl_xor(lo, j, 64);
      lo = ((lane & j) == 0) ? (lo < o ? lo : o) : (lo > o ? lo : o);
    }
    if (lane < KK) kidx[w][lane] = (int)(lo & 0xFFFFFFFFull);
  } else {
    // 128 < n <= CAP: 32 rounds of wave-wide argmin extraction (rare)
    volatile float* vk = ckey[w];
    for (int sel = 0; sel < KK; ++sel) {
      u64 lm = ~0ull;
      int ls = -1;
      for (int s = lane; s < n; s += 64) {
        float d = sqrtf(vk[s]);
        u64 pk = pack_asc(d, (u32)cidx[w][s]);
        if (pk < lm) {
          lm = pk;
          ls = s;
        }
      }
      u64 ww = lm;
#pragma unroll
      for (int j = 32; j > 0; j >>= 1) {
        u64 o = __shfl_xor(ww, j, 64);
        ww = o < ww ? o : ww;
      }
      if (lm == ww && ls >= 0) {
        vk[ls] = INFF;
        kidx[w][sel] = (int)(ww & 0xFFFFFFFFull);
      }
    }
  }
  // same-wave DS ordering: kidx[w] writes visible to this wave's reads

  // ---- IoU of the 32 candidates, top-9 by (iou desc, K-position asc) ----
  {
    u64 v = ~0ull;
    if (lane < KK) {
      float iou = iou_ref(gt, pb[kidx[w][lane]]);
      v = (((u64)(~__float_as_uint(iou))) << 32) | (u64)lane;
    }
    u64 s = bitonic64(v, lane);
    if (lane < NN) {
      int pos = (int)(s & 0xFFFFFFFFull);
      int base = task * NN + lane;
      out[base] = kidx[w][pos];      // pred_idx (original index)
      out[BB * GG * NN + base] = g;  // gt_idx
    }
  }
}

// ============ fused fallback (R9/R11 kernel, proven) for tiny ws ============
#define TTF 8
#define THF 1024
#define RRF (QQ / THF)
#define NWF (THF / 64)
#define CAPF 192
#define ACAPF 96
#define UFF 4

__global__ __launch_bounds__(THF, 4) void atss_fused(
    const float4* __restrict__ pred, const float4* __restrict__ gtb,
    int* __restrict__ out) {
  __shared__ float smin[TTF][THF];
  __shared__ float ckey[TTF][CAPF];
  __shared__ unsigned short cidx[TTF][CAPF];
  __shared__ unsigned short sact[TTF][ACAPF];
  __shared__ int kidx[TTF][KK];
  __shared__ int nC[TTF];
  __shared__ int nAct[TTF];

  const int t = threadIdx.x;
  const int f = blockIdx.x;
  const int b = (f & 7) * 4 + (f >> 7);
  const int g0 = ((f >> 3) & 15) * TTF;
  if (t < TTF) {
    nC[t] = 0;
    nAct[t] = 0;
  }
  float4 G[TTF];
#pragma unroll
  for (int gg = 0; gg < TTF; ++gg) G[gg] = gtb[b * GG + g0 + gg];
  const float4* pb = pred + (size_t)b * QQ;

  float mn[TTF];
#pragma unroll
  for (int gg = 0; gg < TTF; ++gg) mn[gg] = INFF;
  float4 P[UFF];
#pragma unroll
  for (int u = 0; u < UFF; ++u) P[u] = pb[t + u * THF];
#pragma unroll 1
  for (int j = 0; j < RRF; j += UFF) {
    float4 C[UFF];
#pragma unroll
    for (int u = 0; u < UFF; ++u) C[u] = P[u];
    if (j + UFF < RRF) {
#pragma unroll
      for (int u = 0; u < UFF; ++u) P[u] = pb[t + (j + UFF + u) * THF];
    }
#pragma unroll
    for (int u = 0; u < UFF; ++u) {
      float4 p = C[u];
      float pp = fmaf(p.x, p.x, fmaf(p.y, p.y, fmaf(p.z, p.z, p.w * p.w)));
#pragma unroll
      for (int gg = 0; gg < TTF; ++gg) {
        float dot = fmaf(G[gg].x, p.x,
                    fmaf(G[gg].y, p.y, fmaf(G[gg].z, p.z, G[gg].w * p.w)));
        mn[gg] = fminf(mn[gg], fmaf(-2.0f, dot, pp));
      }
    }
  }
#pragma unroll
  for (int gg = 0; gg < TTF; ++gg) smin[gg][t] = mn[gg];
  __syncthreads();

  const int w = t >> 6;
  const int lane = t & 63;
  if (w >= TTF) return;
  const float4 gt = gtb[b * GG + g0 + w];

  float V[NWF];
#pragma unroll
  for (int k = 0; k < NWF; ++k) V[k] = smin[w][lane + 64 * k];
  float m1 = INFF, m2 = INFF;
#pragma unroll
  for (int k = 0; k < NWF; ++k) {
    float v = V[k];
    float nm1 = fminf(m1, v);
    m2 = fminf(m2, fmaxf(m1, v));
    m1 = nm1;
  }
  float A = bitonic64f(m1, lane);
  float Bs = bitonic64f(m2, lane);
  float Br = __shfl(Bs, 63 - lane, 64);
  float m = fminf(A, Br);
#pragma unroll
  for (int j = 32; j > 0; j >>= 1) {
    float o = __shfl_xor(m, j, 64);
    m = ((lane & j) == 0) ? fminf(m, o) : fmaxf(m, o);
  }
  float Us = __shfl(m, 31, 64);
  float gg2 = fmaf(gt.x, gt.x, fmaf(gt.y, gt.y, fmaf(gt.z, gt.z, gt.w * gt.w)));
  const float sUs = Us + fabsf(Us) * 2e-5f + 4e-6f;
  const float T = fmaxf(Us + gg2, 0.0f) * 1.00002f + 4e-6f;

#pragma unroll
  for (int k = 0; k < NWF; ++k) {
    if (V[k] <= sUs) {
      int pos = atomicAdd(&nAct[w], 1);
      if (pos < ACAPF) sact[w][pos] = (unsigned short)(lane + 64 * k);
    }
  }
  int na = nAct[w];
  if (na <= ACAPF) {
    int tot = na * RRF;
    for (int e = lane; e < tot; e += 64) {
      int r = sact[w][e >> 4];
      int i = r + (e & (RRF - 1)) * THF;
      float d2 = dist2_ref(gt, pb[i]);
      if (d2 <= T) {
        int pos = atomicAdd(&nC[w], 1);
        if (pos < CAPF) {
          ckey[w][pos] = d2;
          cidx[w][pos] = (unsigned short)i;
        }
      }
    }
  } else {
    for (int r = lane; r < THF; r += 64) {
      for (int j = 0; j < RRF; ++j) {
        int i = r + j * THF;
        float d2 = dist2_ref(gt, pb[i]);
        if (d2 <= T) {
          int pos = atomicAdd(&nC[w], 1);
          if (pos < CAPF) {
            ckey[w][pos] = d2;
            cidx[w][pos] = (unsigned short)i;
          }
        }
      }
    }
  }
  int n = nC[w];
  if (n > CAPF) {
    if (lane == 0) {
      u64 best[KK];
      for (int l = 0; l < KK; ++l) best[l] = ~0ull;
      for (int i = 0; i < QQ; ++i) {
        float d = sqrtf(dist2_ref(gt, pb[i]));
        u64 pk = pack_asc(d, (u32)i);
        if (pk < best[KK - 1]) {
          int pos = KK - 1;
          while (pos > 0 && best[pos - 1] > pk) {
            best[pos] = best[pos - 1];
            --pos;
          }
          best[pos] = pk;
        }
      }
      for (int l = 0; l < KK; ++l) kidx[w][l] = (int)(best[l] & 0xFFFFFFFFull);
    }
  } else if (n <= 64) {
    u64 v = (lane < n) ? pack_asc(sqrtf(ckey[w][lane]), (u32)cidx[w][lane])
                       : ~0ull;
    u64 s = bitonic64(v, lane);
    if (lane < KK) kidx[w][lane] = (int)(s & 0xFFFFFFFFull);
  } else {
    volatile float* vk = ckey[w];
    for (int sel = 0; sel < KK; ++sel) {
      u64 lm = ~0ull;
      int ls = -1;
      for (int s = lane; s < n; s += 64) {
        float d = sqrtf(vk[s]);
        u64 pk = pack_asc(d, (u32)cidx[w][s]);
        if (pk < lm) {
          lm = pk;
          ls = s;
        }
      }
      u64 ww = lm;
#pragma unroll
      for (int j = 32; j > 0; j >>= 1) {
        u64 o = __shfl_xor(ww, j, 64);
        ww = o < ww ? o : ww;
      }
      if (lm == ww && ls >= 0) {
        vk[ls] = INFF;
        kidx[w][sel] = (int)(ww & 0xFFFFFFFFull);
      }
    }
  }
  {
    u64 v = ~0ull;
    if (lane < KK) {
      float iou = iou_ref(gt, pb[kidx[w][lane]]);
      v = (((u64)(~__float_as_uint(iou))) << 32) | (u64)lane;
    }
    u64 s = bitonic64(v, lane);
    if (lane < NN) {
      int pos = (int)(s & 0xFFFFFFFFull);
      int base = (b * GG + g0 + w) * NN + lane;
      out[base] = kidx[w][pos];
      out[BB * GG * NN + base] = g0 + w;
    }
  }
}

extern "C" void kernel_launch(void* const* d_in, const int* in_sizes, int n_in,
                              void* d_out, int out_size, void* d_ws, size_t ws_size,
                              hipStream_t stream) {
  (void)in_sizes;
  (void)n_in;
  (void)out_size;
  const float4* pred = (const float4*)d_in[0];  // [B, Q, 4] f32
  const float4* gt = (const float4*)d_in[1];    // [B, G, 4] f32
  int* out = (int*)d_out;                       // [2 * B * G * N] int32

  const size_t offS = 0;                                   // 8.39 MB float4
  const size_t offCS = (size_t)BB * QQ * sizeof(float4);   // cellStart
  const size_t offI = offCS + (size_t)BB * (NCELL + 1) * sizeof(int);
  const size_t need = offI + (size_t)BB * QQ * sizeof(unsigned short);

  if (ws_size >= need) {
    float4* S = (float4*)((char*)d_ws + offS);
    int* cellStart = (int*)((char*)d_ws + offCS);
    unsigned short* I = (unsigned short*)((char*)d_ws + offI);
    bin_kernel<<<BB, 1024, 0, stream>>>(pred, S, I, cellStart);
    assign_kernel<<<(GG / (MTH / 64)) * BB, MTH, 0, stream>>>(
        pred, gt, S, I, cellStart, out);
  } else {
    atss_fused<<<(GG / TTF) * BB, THF, 0, stream>>>(pred, gt, out);
  }
}

// Round 13
// 125.422 us; speedup vs baseline: 23.8327x; 23.8327x over previous
//
#include <hip/hip_runtime.h>

#define BB 32
#define QQ 16384
#define GG 128
#define KK 32
#define NN 9
#define CELLS 16
#define NCELL (CELLS * CELLS)
#define CAP 192    // per-wave candidate capacity (expected ~40)
#define MAXR 18    // rows <= 16 (+ sentinel)
#define MTH 512    // main kernel: 8 waves/block, 1 wave per GT
#define RINGMIN 768  // phase-A ring point threshold (half-width >= 2 cells)

typedef unsigned long long u64;
typedef unsigned int u32;

#define INFF __uint_as_float(0x7F800000u)

// packed ascending key: (float bits of nonneg key) << 32 | idx
// lexicographic u64 compare == (value asc, index asc) == jax top_k tie rule
__device__ __forceinline__ u64 pack_asc(float key, u32 idx) {
  return (((u64)__float_as_uint(key)) << 32) | (u64)idx;
}

// EXACT reference squared distance: ((dx^2+dy^2)+dz^2)+dw^2, no contraction.
// ref d = sqrtf(this).
__device__ __forceinline__ float dist2_ref(const float4 g, const float4 p) {
#pragma clang fp contract(off)
  float dx = g.x - p.x;
  float dy = g.y - p.y;
  float dz = g.z - p.z;
  float dw = g.w - p.w;
  float s = dx * dx + dy * dy;
  s = s + dz * dz;
  s = s + dw * dw;
  return s;
}

// IoU exactly as reference (cxcywh -> xyxy, clip, same op order)
__device__ __forceinline__ float iou_ref(const float4 g, const float4 p) {
#pragma clang fp contract(off)
  float gx1 = g.x - 0.5f * g.z, gy1 = g.y - 0.5f * g.w;
  float gx2 = g.x + 0.5f * g.z, gy2 = g.y + 0.5f * g.w;
  float px1 = p.x - 0.5f * p.z, py1 = p.y - 0.5f * p.w;
  float px2 = p.x + 0.5f * p.z, py2 = p.y + 0.5f * p.w;
  float ltx = fmaxf(gx1, px1), lty = fmaxf(gy1, py1);
  float rbx = fminf(gx2, px2), rby = fminf(gy2, py2);
  float wx = fmaxf(rbx - ltx, 0.0f), wy = fmaxf(rby - lty, 0.0f);
  float inter = wx * wy;
  float aa = (gx2 - gx1) * (gy2 - gy1);
  float ab = (px2 - px1) * (py2 - py1);
  return inter / ((aa + ab) - inter);
}

// full ascending bitonic sort across one 64-lane wave, u64 keys
__device__ __forceinline__ u64 bitonic64(u64 v, int lane) {
#pragma unroll
  for (int k = 2; k <= 64; k <<= 1) {
#pragma unroll
    for (int j = k >> 1; j > 0; j >>= 1) {
      u64 o = __shfl_xor(v, j, 64);
      bool up = ((lane & k) == 0);
      bool lower = ((lane & j) == 0);
      v = (lower == up) ? (v < o ? v : o) : (v > o ? v : o);
    }
  }
  return v;
}

// full ascending bitonic sort across one 64-lane wave, float keys
__device__ __forceinline__ float bitonic64f(float v, int lane) {
#pragma unroll
  for (int k = 2; k <= 64; k <<= 1) {
#pragma unroll
    for (int j = k >> 1; j > 0; j >>= 1) {
      float o = __shfl_xor(v, j, 64);
      bool up = ((lane & k) == 0);
      bool lower = ((lane & j) == 0);
      v = (lower == up) ? fminf(v, o) : fmaxf(v, o);
    }
  }
  return v;
}

// 32nd smallest of 128 kept values (2 per lane, m1 <= m2), wave-uniform.
__device__ __forceinline__ float kept128_32nd(float m1, float m2, int lane) {
  float A = bitonic64f(m1, lane);
  float Bs = bitonic64f(m2, lane);
  float Br = __shfl(Bs, 63 - lane, 64);
  float m = fminf(A, Br);  // bitonic, holds the 64 smallest
#pragma unroll
  for (int j = 32; j > 0; j >>= 1) {
    float o = __shfl_xor(m, j, 64);
    m = ((lane & j) == 0) ? fminf(m, o) : fmaxf(m, o);
  }
  return __shfl(m, 31, 64);
}

// ==================== kernel 1: bin preds by (cx,cy) cell ====================
__global__ __launch_bounds__(1024) void bin_kernel(
    const float4* __restrict__ pred, float4* __restrict__ S,
    unsigned short* __restrict__ I, int* __restrict__ cellStart) {
  __shared__ int cnt[NCELL];
  __shared__ int off[NCELL];
  const int t = threadIdx.x;
  const int b = blockIdx.x;
  if (t < NCELL) cnt[t] = 0;
  __syncthreads();
  const float4* pb = pred + (size_t)b * QQ;
  int cells[QQ / 1024];
#pragma unroll
  for (int j = 0; j < QQ / 1024; ++j) {
    float4 p = pb[t + j * 1024];
    int cx = min(CELLS - 1, max(0, (int)(p.x * CELLS)));
    int cy = min(CELLS - 1, max(0, (int)(p.y * CELLS)));
    int c = cy * CELLS + cx;
    cells[j] = c;
    atomicAdd(&cnt[c], 1);
  }
  __syncthreads();
  if (t == 0) {
    int acc = 0;
    for (int c = 0; c < NCELL; ++c) {
      off[c] = acc;
      acc += cnt[c];
    }
  }
  __syncthreads();
  if (t < NCELL) cellStart[b * (NCELL + 1) + t] = off[t];
  if (t == 0) cellStart[b * (NCELL + 1) + NCELL] = QQ;
  __syncthreads();  // snapshot off before scatter mutates it
#pragma unroll
  for (int j = 0; j < QQ / 1024; ++j) {
    int i = t + j * 1024;
    float4 p = pb[i];
    int pos = atomicAdd(&off[cells[j]], 1);
    S[(size_t)b * QQ + pos] = p;
    I[(size_t)b * QQ + pos] = (unsigned short)i;
  }
}

// ==================== kernel 2: one wave per GT ====================
__global__ __launch_bounds__(MTH) void assign_kernel(
    const float4* __restrict__ pred, const float4* __restrict__ gtb,
    const float4* __restrict__ S, const unsigned short* __restrict__ I,
    const int* __restrict__ cellStart, int* __restrict__ out) {
  __shared__ float ckey[MTH / 64][CAP];
  __shared__ unsigned short cidx[MTH / 64][CAP];
  __shared__ int rowS[MTH / 64][MAXR];
  __shared__ int rowC[MTH / 64][MAXR + 1];
  __shared__ int kidx[MTH / 64][KK];
  __shared__ int nC[MTH / 64];

  const int t = threadIdx.x;
  const int w = t >> 6, lane = t & 63;
  // XCD swizzle: the 16 blocks of one batch share an XCD -> S_b slice in L2
  const int blk = blockIdx.x;
  const int b = (blk & 7) * 4 + (blk >> 7);
  const int g = ((blk >> 3) & 15) * (MTH / 64) + w;
  const int task = b * GG + g;
  if (lane == 0) nC[w] = 0;

  const float4 gt = gtb[task];
  const float4* Sb = S + (size_t)b * QQ;
  const unsigned short* Ib = I + (size_t)b * QQ;
  const int* cs = cellStart + b * (NCELL + 1);
  const float4* pb = pred + (size_t)b * QQ;

  const int cgx = min(CELLS - 1, max(0, (int)(gt.x * CELLS)));
  const int cgy = min(CELLS - 1, max(0, (int)(gt.y * CELLS)));

  // ---- phase A rows: expand square ring until >= RINGMIN points ----
  // RINGMIN=768 -> half-width >= 2 cells (0.125) even at edges, so the
  // sample covers most of the true 32-NN 4D ball (r ~ 0.14) -> U2 tight.
  int cnt = 0, nR = 0;
  for (int r = 1; r <= CELLS; ++r) {
    int y0 = max(0, cgy - r), y1 = min(CELLS - 1, cgy + r);
    int x0 = max(0, cgx - r), x1 = min(CELLS - 1, cgx + r);
    nR = y1 - y0 + 1;
    int len = 0, st = 0;
    if (lane < nR) {
      int y = y0 + lane;
      st = cs[y * CELLS + x0];
      len = cs[y * CELLS + x1 + 1] - st;
    }
    int incl = len;
#pragma unroll
    for (int d = 1; d < 64; d <<= 1) {
      int o = __shfl_up(incl, d, 64);
      if (lane >= d) incl += o;
    }
    cnt = __shfl(incl, nR - 1, 64);
    if (lane < nR) {
      rowS[w][lane] = st;
      rowC[w][lane] = incl - len;
    }
    if (lane == nR) rowC[w][nR] = incl;  // == cnt (len 0 for lane >= nR)
    if (cnt >= RINGMIN || r == CELLS) break;
  }

  // ---- phase A scan: exact d2, per-lane 2 smallest (flattened gq = lane
  // mod 64 -> disjoint element assignment; cnt >= 128 -> every lane >= 2
  // elements -> 128 kept values from distinct elements).
  float m1 = INFF, m2 = INFF;
  {
    int ri = 0;
    for (int gq = lane; gq < cnt; gq += 64) {
      while (gq >= rowC[w][ri + 1]) ++ri;
      int e = rowS[w][ri] + (gq - rowC[w][ri]);
      float d2 = dist2_ref(gt, Sb[e]);
      float nm1 = fminf(m1, d2);
      m2 = fminf(m2, fmaxf(m1, d2));
      m1 = nm1;
    }
  }

  // ---- U2 = 32nd smallest of the 128 kept exact d2 values ----
  // The 32 kept values <= U2 are 32 distinct elements -> U2 >= true 32nd d2.
  float U2 = kept128_32nd(m1, m2, lane);
  // only sqrt-collapse margin needed (all arithmetic is exact ref-form):
  float T = U2 * 1.00002f + 4e-6f;

  // ---- phase B rows: all cells intersecting the 2D disk of radius
  // sqrt(T) around (gt.x, gt.y). d2<=T => dcx^2+dcy^2<=T => the point's
  // cell is in this set (1e-4 margins crush float/binning slop; margins
  // only ADD cells -> conservative).
  {
    float radT = sqrtf(T) + 1e-4f;
    int yLo = max(0, (int)floorf((gt.y - radT) * CELLS));
    int yHi = min(CELLS - 1, (int)floorf((gt.y + radT) * CELLS));
    int nR2 = yHi - yLo + 1;
    int len = 0, st = 0;
    if (lane < nR2) {
      int y = yLo + lane;
      float ylo = (float)y / CELLS, yhi = (float)(y + 1) / CELLS;
      float dy = fmaxf(0.0f, fmaxf(ylo - gt.y, gt.y - yhi));
      dy = fmaxf(0.0f, dy - 1e-4f);
      float rem = T - dy * dy;
      if (rem >= 0.0f) {
        float dx = sqrtf(rem) + 1e-4f;
        int x0 = max(0, (int)floorf((gt.x - dx) * CELLS));
        int x1 = min(CELLS - 1, (int)floorf((gt.x + dx) * CELLS));
        st = cs[y * CELLS + x0];
        len = cs[y * CELLS + x1 + 1] - st;
      }
    }
    int incl = len;
#pragma unroll
    for (int d = 1; d < 64; d <<= 1) {
      int o = __shfl_up(incl, d, 64);
      if (lane >= d) incl += o;
    }
    int cnt2 = __shfl(incl, nR2 - 1, 64);
    if (lane < nR2) {
      rowS[w][lane] = st;
      rowC[w][lane] = incl - len;
    }
    if (lane == nR2) rowC[w][nR2] = incl;

    // ---- phase B scan: collect exact-d2 candidates (orig idx from Ib) ----
    int ri = 0;
    for (int gq = lane; gq < cnt2; gq += 64) {
      while (gq >= rowC[w][ri + 1]) ++ri;
      int e = rowS[w][ri] + (gq - rowC[w][ri]);
      float d2 = dist2_ref(gt, Sb[e]);
      if (d2 <= T) {
        int pos = atomicAdd(&nC[w], 1);
        if (pos < CAP) {
          ckey[w][pos] = d2;
          cidx[w][pos] = Ib[e];
        }
      }
    }
  }
  int n = nC[w];  // >= 32: every ref-top-32 point has d2 <= U2 <= T

  // ---- rescue (rare): T was loose -> recompute tight bound by full exact
  // scan (kept-2 per lane over i = lane mod 64, 256 elems/lane -> 128 kept
  // from distinct elements), then recollect. Wave-parallel (~2 us), replaces
  // the old serial straggler that cost ~3 ms/dispatch in R12.
  if (n > CAP) {
    float r1 = INFF, r2 = INFF;
    for (int i = lane; i < QQ; i += 64) {
      float d2 = dist2_ref(gt, pb[i]);
      float nm1 = fminf(r1, d2);
      r2 = fminf(r2, fmaxf(r1, d2));
      r1 = nm1;
    }
    float U2t = kept128_32nd(r1, r2, lane);
    T = U2t * 1.00002f + 4e-6f;
    if (lane == 0) nC[w] = 0;  // same-wave DS ordering
    for (int i = lane; i < QQ; i += 64) {
      float d2 = dist2_ref(gt, pb[i]);
      if (d2 <= T) {
        int pos = atomicAdd(&nC[w], 1);
        if (pos < CAP) {
          ckey[w][pos] = d2;
          cidx[w][pos] = (unsigned short)i;
        }
      }
    }
    n = nC[w];  // ~36 expected with the tight bound
  }

  // ---- select top-32 by (d, idx) ascending; d = sqrtf(d2) (IEEE == jnp)
  if (n > CAP) {
    // ultimate safety net (never hit: tight-bound n' > 192 needs the 192
    // smallest elements concentrated on < 16 lanes)
    if (lane == 0) {
      u64 best[KK];
      for (int l = 0; l < KK; ++l) best[l] = ~0ull;
      for (int i = 0; i < QQ; ++i) {
        float d = sqrtf(dist2_ref(gt, pb[i]));
        u64 pk = pack_asc(d, (u32)i);
        if (pk < best[KK - 1]) {
          int pos = KK - 1;
          while (pos > 0 && best[pos - 1] > pk) {
            best[pos] = best[pos - 1];
            --pos;
          }
          best[pos] = pk;
        }
      }
      for (int l = 0; l < KK; ++l) kidx[w][l] = (int)(best[l] & 0xFFFFFFFFull);
    }
  } else if (n <= 64) {
    // fast path (expected ~95%)
    u64 v = (lane < n) ? pack_asc(sqrtf(ckey[w][lane]), (u32)cidx[w][lane])
                       : ~0ull;
    u64 s = bitonic64(v, lane);
    if (lane < KK) kidx[w][lane] = (int)(s & 0xFFFFFFFFull);
  } else if (n <= 128) {
    // two-register bitonic merge: smallest 64 of <=128, sorted
    u64 v1 = (lane < n) ? pack_asc(sqrtf(ckey[w][lane]), (u32)cidx[w][lane])
                        : ~0ull;
    u64 v2 = (64 + lane < n)
                 ? pack_asc(sqrtf(ckey[w][64 + lane]), (u32)cidx[w][64 + lane])
                 : ~0ull;
    u64 s1 = bitonic64(v1, lane);
    u64 s2 = bitonic64(v2, lane);
    u64 s2r = __shfl(s2, 63 - lane, 64);
    u64 lo = s1 < s2r ? s1 : s2r;  // bitonic, holds the 64 smallest
#pragma unroll
    for (int j = 32; j > 0; j >>= 1) {
      u64 o = __shfl_xor(lo, j, 64);
      lo = ((lane & j) == 0) ? (lo < o ? lo : o) : (lo > o ? lo : o);
    }
    if (lane < KK) kidx[w][lane] = (int)(lo & 0xFFFFFFFFull);
  } else {
    // 128 < n <= CAP: 32 rounds of wave-wide argmin extraction (rare)
    volatile float* vk = ckey[w];
    for (int sel = 0; sel < KK; ++sel) {
      u64 lm = ~0ull;
      int ls = -1;
      for (int s = lane; s < n; s += 64) {
        float d = sqrtf(vk[s]);
        u64 pk = pack_asc(d, (u32)cidx[w][s]);
        if (pk < lm) {
          lm = pk;
          ls = s;
        }
      }
      u64 ww = lm;
#pragma unroll
      for (int j = 32; j > 0; j >>= 1) {
        u64 o = __shfl_xor(ww, j, 64);
        ww = o < ww ? o : ww;
      }
      if (lm == ww && ls >= 0) {
        vk[ls] = INFF;
        kidx[w][sel] = (int)(ww & 0xFFFFFFFFull);
      }
    }
  }
  // same-wave DS ordering: kidx[w] writes visible to this wave's reads

  // ---- IoU of the 32 candidates, top-9 by (iou desc, K-position asc) ----
  {
    u64 v = ~0ull;
    if (lane < KK) {
      float iou = iou_ref(gt, pb[kidx[w][lane]]);
      v = (((u64)(~__float_as_uint(iou))) << 32) | (u64)lane;
    }
    u64 s = bitonic64(v, lane);
    if (lane < NN) {
      int pos = (int)(s & 0xFFFFFFFFull);
      int base = task * NN + lane;
      out[base] = kidx[w][pos];      // pred_idx (original index)
      out[BB * GG * NN + base] = g;  // gt_idx
    }
  }
}

// ============ fused fallback (R9/R11 kernel, proven) for tiny ws ============
#define TTF 8
#define THF 1024
#define RRF (QQ / THF)
#define NWF (THF / 64)
#define CAPF 192
#define ACAPF 96
#define UFF 4

__global__ __launch_bounds__(THF, 4) void atss_fused(
    const float4* __restrict__ pred, const float4* __restrict__ gtb,
    int* __restrict__ out) {
  __shared__ float smin[TTF][THF];
  __shared__ float ckey[TTF][CAPF];
  __shared__ unsigned short cidx[TTF][CAPF];
  __shared__ unsigned short sact[TTF][ACAPF];
  __shared__ int kidx[TTF][KK];
  __shared__ int nC[TTF];
  __shared__ int nAct[TTF];

  const int t = threadIdx.x;
  const int f = blockIdx.x;
  const int b = (f & 7) * 4 + (f >> 7);
  const int g0 = ((f >> 3) & 15) * TTF;
  if (t < TTF) {
    nC[t] = 0;
    nAct[t] = 0;
  }
  float4 G[TTF];
#pragma unroll
  for (int gg = 0; gg < TTF; ++gg) G[gg] = gtb[b * GG + g0 + gg];
  const float4* pb = pred + (size_t)b * QQ;

  float mn[TTF];
#pragma unroll
  for (int gg = 0; gg < TTF; ++gg) mn[gg] = INFF;
  float4 P[UFF];
#pragma unroll
  for (int u = 0; u < UFF; ++u) P[u] = pb[t + u * THF];
#pragma unroll 1
  for (int j = 0; j < RRF; j += UFF) {
    float4 C[UFF];
#pragma unroll
    for (int u = 0; u < UFF; ++u) C[u] = P[u];
    if (j + UFF < RRF) {
#pragma unroll
      for (int u = 0; u < UFF; ++u) P[u] = pb[t + (j + UFF + u) * THF];
    }
#pragma unroll
    for (int u = 0; u < UFF; ++u) {
      float4 p = C[u];
      float pp = fmaf(p.x, p.x, fmaf(p.y, p.y, fmaf(p.z, p.z, p.w * p.w)));
#pragma unroll
      for (int gg = 0; gg < TTF; ++gg) {
        float dot = fmaf(G[gg].x, p.x,
                    fmaf(G[gg].y, p.y, fmaf(G[gg].z, p.z, G[gg].w * p.w)));
        mn[gg] = fminf(mn[gg], fmaf(-2.0f, dot, pp));
      }
    }
  }
#pragma unroll
  for (int gg = 0; gg < TTF; ++gg) smin[gg][t] = mn[gg];
  __syncthreads();

  const int w = t >> 6;
  const int lane = t & 63;
  if (w >= TTF) return;
  const float4 gt = gtb[b * GG + g0 + w];

  float V[NWF];
#pragma unroll
  for (int k = 0; k < NWF; ++k) V[k] = smin[w][lane + 64 * k];
  float m1 = INFF, m2 = INFF;
#pragma unroll
  for (int k = 0; k < NWF; ++k) {
    float v = V[k];
    float nm1 = fminf(m1, v);
    m2 = fminf(m2, fmaxf(m1, v));
    m1 = nm1;
  }
  float A = bitonic64f(m1, lane);
  float Bs = bitonic64f(m2, lane);
  float Br = __shfl(Bs, 63 - lane, 64);
  float m = fminf(A, Br);
#pragma unroll
  for (int j = 32; j > 0; j >>= 1) {
    float o = __shfl_xor(m, j, 64);
    m = ((lane & j) == 0) ? fminf(m, o) : fmaxf(m, o);
  }
  float Us = __shfl(m, 31, 64);
  float gg2 = fmaf(gt.x, gt.x, fmaf(gt.y, gt.y, fmaf(gt.z, gt.z, gt.w * gt.w)));
  const float sUs = Us + fabsf(Us) * 2e-5f + 4e-6f;
  const float T = fmaxf(Us + gg2, 0.0f) * 1.00002f + 4e-6f;

#pragma unroll
  for (int k = 0; k < NWF; ++k) {
    if (V[k] <= sUs) {
      int pos = atomicAdd(&nAct[w], 1);
      if (pos < ACAPF) sact[w][pos] = (unsigned short)(lane + 64 * k);
    }
  }
  int na = nAct[w];
  if (na <= ACAPF) {
    int tot = na * RRF;
    for (int e = lane; e < tot; e += 64) {
      int r = sact[w][e >> 4];
      int i = r + (e & (RRF - 1)) * THF;
      float d2 = dist2_ref(gt, pb[i]);
      if (d2 <= T) {
        int pos = atomicAdd(&nC[w], 1);
        if (pos < CAPF) {
          ckey[w][pos] = d2;
          cidx[w][pos] = (unsigned short)i;
        }
      }
    }
  } else {
    for (int r = lane; r < THF; r += 64) {
      for (int j = 0; j < RRF; ++j) {
        int i = r + j * THF;
        float d2 = dist2_ref(gt, pb[i]);
        if (d2 <= T) {
          int pos = atomicAdd(&nC[w], 1);
          if (pos < CAPF) {
            ckey[w][pos] = d2;
            cidx[w][pos] = (unsigned short)i;
          }
        }
      }
    }
  }
  int n = nC[w];
  if (n > CAPF) {
    if (lane == 0) {
      u64 best[KK];
      for (int l = 0; l < KK; ++l) best[l] = ~0ull;
      for (int i = 0; i < QQ; ++i) {
        float d = sqrtf(dist2_ref(gt, pb[i]));
        u64 pk = pack_asc(d, (u32)i);
        if (pk < best[KK - 1]) {
          int pos = KK - 1;
          while (pos > 0 && best[pos - 1] > pk) {
            best[pos] = best[pos - 1];
            --pos;
          }
          best[pos] = pk;
        }
      }
      for (int l = 0; l < KK; ++l) kidx[w][l] = (int)(best[l] & 0xFFFFFFFFull);
    }
  } else if (n <= 64) {
    u64 v = (lane < n) ? pack_asc(sqrtf(ckey[w][lane]), (u32)cidx[w][lane])
                       : ~0ull;
    u64 s = bitonic64(v, lane);
    if (lane < KK) kidx[w][lane] = (int)(s & 0xFFFFFFFFull);
  } else {
    volatile float* vk = ckey[w];
    for (int sel = 0; sel < KK; ++sel) {
      u64 lm = ~0ull;
      int ls = -1;
      for (int s = lane; s < n; s += 64) {
        float d = sqrtf(vk[s]);
        u64 pk = pack_asc(d, (u32)cidx[w][s]);
        if (pk < lm) {
          lm = pk;
          ls = s;
        }
      }
      u64 ww = lm;
#pragma unroll
      for (int j = 32; j > 0; j >>= 1) {
        u64 o = __shfl_xor(ww, j, 64);
        ww = o < ww ? o : ww;
      }
      if (lm == ww && ls >= 0) {
        vk[ls] = INFF;
        kidx[w][sel] = (int)(ww & 0xFFFFFFFFull);
      }
    }
  }
  {
    u64 v = ~0ull;
    if (lane < KK) {
      float iou = iou_ref(gt, pb[kidx[w][lane]]);
      v = (((u64)(~__float_as_uint(iou))) << 32) | (u64)lane;
    }
    u64 s = bitonic64(v, lane);
    if (lane < NN) {
      int pos = (int)(s & 0xFFFFFFFFull);
      int base = (b * GG + g0 + w) * NN + lane;
      out[base] = kidx[w][pos];
      out[BB * GG * NN + base] = g0 + w;
    }
  }
}

extern "C" void kernel_launch(void* const* d_in, const int* in_sizes, int n_in,
                              void* d_out, int out_size, void* d_ws, size_t ws_size,
                              hipStream_t stream) {
  (void)in_sizes;
  (void)n_in;
  (void)out_size;
  const float4* pred = (const float4*)d_in[0];  // [B, Q, 4] f32
  const float4* gt = (const float4*)d_in[1];    // [B, G, 4] f32
  int* out = (int*)d_out;                       // [2 * B * G * N] int32

  const size_t offS = 0;                                   // 8.39 MB float4
  const size_t offCS = (size_t)BB * QQ * sizeof(float4);   // cellStart
  const size_t offI = offCS + (size_t)BB * (NCELL + 1) * sizeof(int);
  const size_t need = offI + (size_t)BB * QQ * sizeof(unsigned short);

  if (ws_size >= need) {
    float4* S = (float4*)((char*)d_ws + offS);
    int* cellStart = (int*)((char*)d_ws + offCS);
    unsigned short* I = (unsigned short*)((char*)d_ws + offI);
    bin_kernel<<<BB, 1024, 0, stream>>>(pred, S, I, cellStart);
    assign_kernel<<<(GG / (MTH / 64)) * BB, MTH, 0, stream>>>(
        pred, gt, S, I, cellStart, out);
  } else {
    atss_fused<<<(GG / TTF) * BB, THF, 0, stream>>>(pred, gt, out);
  }
}

// Round 14
// 79.317 us; speedup vs baseline: 37.6863x; 1.5813x over previous
//
#include <hip/hip_runtime.h>

#define BB 32
#define QQ 16384
#define GG 128
#define KK 32
#define NN 9
#define TT 8      // GTs per block; tail waves 0..7, waves 8..15 exit early
#define TH 1024   // 16 waves; 512 blocks -> 2 blocks/CU
#define RR (QQ / TH)  // 16 elements per thread-range
#define NW (TH / 64)
#define CAP 192   // per-GT candidate capacity (expected ~40 with tight U)
#define ACAP 96   // per-GT active-range capacity (expected ~36)
#define UF 4      // load prefetch batch

typedef unsigned long long u64;
typedef unsigned int u32;

#define INFF __uint_as_float(0x7F800000u)

// packed ascending key: (float bits of nonneg key) << 32 | idx
// lexicographic u64 compare == (value asc, index asc) == jax top_k tie rule
__device__ __forceinline__ u64 pack_asc(float key, u32 idx) {
  return (((u64)__float_as_uint(key)) << 32) | (u64)idx;
}

// EXACT reference squared distance: ((dx^2+dy^2)+dz^2)+dw^2, no contraction.
// ref d = sqrtf(this).
__device__ __forceinline__ float dist2_ref(const float4 g, const float4 p) {
#pragma clang fp contract(off)
  float dx = g.x - p.x;
  float dy = g.y - p.y;
  float dz = g.z - p.z;
  float dw = g.w - p.w;
  float s = dx * dx + dy * dy;
  s = s + dz * dz;
  s = s + dw * dw;
  return s;
}

// IoU exactly as reference (cxcywh -> xyxy, clip, same op order)
__device__ __forceinline__ float iou_ref(const float4 g, const float4 p) {
#pragma clang fp contract(off)
  float gx1 = g.x - 0.5f * g.z, gy1 = g.y - 0.5f * g.w;
  float gx2 = g.x + 0.5f * g.z, gy2 = g.y + 0.5f * g.w;
  float px1 = p.x - 0.5f * p.z, py1 = p.y - 0.5f * p.w;
  float px2 = p.x + 0.5f * p.z, py2 = p.y + 0.5f * p.w;
  float ltx = fmaxf(gx1, px1), lty = fmaxf(gy1, py1);
  float rbx = fminf(gx2, px2), rby = fminf(gy2, py2);
  float wx = fmaxf(rbx - ltx, 0.0f), wy = fmaxf(rby - lty, 0.0f);
  float inter = wx * wy;
  float aa = (gx2 - gx1) * (gy2 - gy1);
  float ab = (px2 - px1) * (py2 - py1);
  return inter / ((aa + ab) - inter);
}

// full ascending bitonic sort across one 64-lane wave, u64 keys
__device__ __forceinline__ u64 bitonic64(u64 v, int lane) {
#pragma unroll
  for (int k = 2; k <= 64; k <<= 1) {
#pragma unroll
    for (int j = k >> 1; j > 0; j >>= 1) {
      u64 o = __shfl_xor(v, j, 64);
      bool up = ((lane & k) == 0);
      bool lower = ((lane & j) == 0);
      v = (lower == up) ? (v < o ? v : o) : (v > o ? v : o);
    }
  }
  return v;
}

// full ascending bitonic sort across one 64-lane wave, float keys
// (handles negatives; values finite or +inf padding, never NaN)
__device__ __forceinline__ float bitonic64f(float v, int lane) {
#pragma unroll
  for (int k = 2; k <= 64; k <<= 1) {
#pragma unroll
    for (int j = k >> 1; j > 0; j >>= 1) {
      float o = __shfl_xor(v, j, 64);
      bool up = ((lane & k) == 0);
      bool lower = ((lane & j) == 0);
      v = (lower == up) ? fminf(v, o) : fmaxf(v, o);
    }
  }
  return v;
}

__global__ __launch_bounds__(TH, 8) void atss_kernel(
    const float4* __restrict__ pred, const float4* __restrict__ gtb,
    int* __restrict__ out) {
  __shared__ float smin[TT][TH];            // 32 KB
  __shared__ float ckey[TT][CAP];           // 6 KB
  __shared__ unsigned short cidx[TT][CAP];  // 3 KB
  __shared__ unsigned short sact[TT][ACAP]; // 1.5 KB
  __shared__ int kidx[TT][KK];              // 1 KB
  __shared__ int nC[TT];
  __shared__ int nAct[TT];

  const int t = threadIdx.x;
  // XCD swizzle (round-robin block->XCD assumed): the 16 blocks of one
  // batch share an XCD; its L2 holds that batch's 256 KB pred slice.
  const int f = blockIdx.x;
  const int b = (f & 7) * 4 + (f >> 7);
  const int g0 = ((f >> 3) & 15) * TT;

  if (t < TT) {
    nC[t] = 0;
    nAct[t] = 0;
  }

  // 8 GT boxes from block-uniform addresses -> scalar loads / SGPRs
  float4 G[TT];
#pragma unroll
  for (int gg = 0; gg < TT; ++gg) G[gg] = gtb[b * GG + g0 + gg];

  const float4* pb = pred + (size_t)b * QQ;

  // ---- pass 1: per-thread min of s = |p|^2 - 2 g.p over 16 elements ----
  // (d2 shifted by per-GT constant -|g|^2 -> same ordering). One float4
  // load feeds 8 GTs; 4 loads in flight.
  float mn[TT];
#pragma unroll
  for (int gg = 0; gg < TT; ++gg) mn[gg] = INFF;

  float4 P[UF];
#pragma unroll
  for (int u = 0; u < UF; ++u) P[u] = pb[t + u * TH];
#pragma unroll
  for (int j = 0; j < RR; j += UF) {
    float4 C[UF];
#pragma unroll
    for (int u = 0; u < UF; ++u) C[u] = P[u];
    if (j + UF < RR) {
#pragma unroll
      for (int u = 0; u < UF; ++u) P[u] = pb[t + (j + UF + u) * TH];
    }
#pragma unroll
    for (int u = 0; u < UF; ++u) {
      float4 p = C[u];
      float pp = fmaf(p.x, p.x, fmaf(p.y, p.y, fmaf(p.z, p.z, p.w * p.w)));
#pragma unroll
      for (int gg = 0; gg < TT; ++gg) {
        float dot = fmaf(G[gg].x, p.x,
                    fmaf(G[gg].y, p.y,
                    fmaf(G[gg].z, p.z, G[gg].w * p.w)));
        mn[gg] = fminf(mn[gg], fmaf(-2.0f, dot, pp));
      }
    }
  }
#pragma unroll
  for (int gg = 0; gg < TT; ++gg) smin[gg][t] = mn[gg];

  __syncthreads();  // the ONLY block-wide barrier

  const int w = t >> 6;
  const int lane = t & 63;
  if (w >= TT) return;  // waves 8..15 done; frees wave slots

  // ================= wave w handles GT (g0 + w) alone =================
  const float4 gt = gtb[b * GG + g0 + w];  // wave-uniform reload

  // ---- load this GT's 1024 thread-mins; lane owns threads {lane + 64k}
  // (conflict-free stride-4B ds reads; a disjoint range partition).
  float V[NW];
#pragma unroll
  for (int k = 0; k < NW; ++k) V[k] = smin[w][lane + 64 * k];

  // ---- per-lane 2 smallest of its 16 values (branchless) ----
  float m1 = INFF, m2 = INFF;
#pragma unroll
  for (int k = 0; k < NW; ++k) {
    float v = V[k];
    float nm1 = fminf(m1, v);
    m2 = fminf(m2, fmaxf(m1, v));
    m1 = nm1;
  }

  // ---- U = 32nd smallest of the 128 kept values (2 per lane) ----
  // Kept set is a subset of the 1024 thread-mins -> its 32nd smallest is
  // >= the true 32nd smallest thread-min; the 32 kept values <= U are 32
  // DISTINCT threads' range-mins -> >= 32 distinct elements have approx
  // s <= U. Tight: E[n] ~36, P(n>64) ~0 (proven R9: -16 us vs loose bound).
  float A = bitonic64f(m1, lane);
  float Bs = bitonic64f(m2, lane);
  float Br = __shfl(Bs, 63 - lane, 64);  // descending B
  float m = fminf(A, Br);  // bitonic sequence holding the 64 smallest
#pragma unroll
  for (int j = 32; j > 0; j >>= 1) {  // sort bitonic -> ascending
    float o = __shfl_xor(m, j, 64);
    m = ((lane & j) == 0) ? fminf(m, o) : fmaxf(m, o);
  }
  float Us = __shfl(m, 31, 64);  // 32nd smallest, wave-uniform
  float gg2 = fmaf(gt.x, gt.x,
              fmaf(gt.y, gt.y, fmaf(gt.z, gt.z, gt.w * gt.w)));
  // Inflation covers fma-form vs ref-form rounding (~5e-7 abs) and
  // sqrt-collapse ties (margins proven in R5-R13).
  const float sUs = Us + fabsf(Us) * 2e-5f + 4e-6f;          // s-space test
  const float T = fmaxf(Us + gg2, 0.0f) * 1.00002f + 4e-6f;  // d2-space test

  // ---- compact active ranges (expected ~36 of 1024) ----
#pragma unroll
  for (int k = 0; k < NW; ++k) {
    if (V[k] <= sUs) {
      int pos = atomicAdd(&nAct[w], 1);
      if (pos < ACAP) sact[w][pos] = (unsigned short)(lane + 64 * k);
    }
  }
  int na = nAct[w];  // same-wave DS ordering: no barrier needed

  // ---- exact-d2 collection over active ranges ----
  if (na <= ACAP) {
    for (int it = lane; it < na; it += 64) {
      int r = sact[w][it];
      for (int j = 0; j < RR; ++j) {
        int i = r + j * TH;
        float d2 = dist2_ref(gt, pb[i]);
        if (d2 <= T) {
          int pos = atomicAdd(&nC[w], 1);
          if (pos < CAP) {
            ckey[w][pos] = d2;
            cidx[w][pos] = (unsigned short)i;
          }
        }
      }
    }
  } else {
    // pathological: dense wave rescan of all ranges
    for (int r = lane; r < TH; r += 64) {
      for (int j = 0; j < RR; ++j) {
        int i = r + j * TH;
        float d2 = dist2_ref(gt, pb[i]);
        if (d2 <= T) {
          int pos = atomicAdd(&nC[w], 1);
          if (pos < CAP) {
            ckey[w][pos] = d2;
            cidx[w][pos] = (unsigned short)i;
          }
        }
      }
    }
  }
  int n = nC[w];  // >= 32 guaranteed by the bound argument

  // ---- select top-32 by (d, idx) ascending; d = sqrtf(d2) (IEEE == jnp)
  if (n > CAP) {
    // pathological-only exact serial fallback
    if (lane == 0) {
      u64 best[KK];
      for (int l = 0; l < KK; ++l) best[l] = ~0ull;
      for (int i = 0; i < QQ; ++i) {
        float d = sqrtf(dist2_ref(gt, pb[i]));
        u64 pk = pack_asc(d, (u32)i);
        if (pk < best[KK - 1]) {
          int pos = KK - 1;
          while (pos > 0 && best[pos - 1] > pk) {
            best[pos] = best[pos - 1];
            --pos;
          }
          best[pos] = pk;
        }
      }
      for (int l = 0; l < KK; ++l) kidx[w][l] = (int)(best[l] & 0xFFFFFFFFull);
    }
  } else if (n <= 64) {
    // fast path (~100% with tight U): one wave bitonic sort
    u64 v = (lane < n) ? pack_asc(sqrtf(ckey[w][lane]), (u32)cidx[w][lane])
                       : ~0ull;
    u64 s = bitonic64(v, lane);
    if (lane < KK) kidx[w][lane] = (int)(s & 0xFFFFFFFFull);
  } else {
    // 64 < n <= CAP: 32 rounds of wave-wide argmin extraction (rare)
    volatile float* vk = ckey[w];
    for (int sel = 0; sel < KK; ++sel) {
      u64 lm = ~0ull;
      int ls = -1;
      for (int s = lane; s < n; s += 64) {
        float d = sqrtf(vk[s]);  // sqrtf(inf)=inf for consumed slots
        u64 pk = pack_asc(d, (u32)cidx[w][s]);
        if (pk < lm) {
          lm = pk;
          ls = s;
        }
      }
      u64 ww = lm;
#pragma unroll
      for (int j = 32; j > 0; j >>= 1) {
        u64 o = __shfl_xor(ww, j, 64);
        ww = o < ww ? o : ww;
      }
      if (lm == ww && ls >= 0) {  // unique winner (idx unique)
        vk[ls] = INFF;            // mark used
        kidx[w][sel] = (int)(ww & 0xFFFFFFFFull);
      }
    }
  }
  // same-wave DS ordering: kidx[w] writes visible to this wave's reads

  // ---- IoU of the 32 candidates, top-9 by (iou desc, position asc) ----
  {
    u64 v = ~0ull;
    if (lane < KK) {
      float iou = iou_ref(gt, pb[kidx[w][lane]]);
      // ~bits(iou) strictly decreasing in iou (iou >= 0): ascending packed
      // sort == descending iou, ties -> lower K-position first
      v = (((u64)(~__float_as_uint(iou))) << 32) | (u64)lane;
    }
    u64 s = bitonic64(v, lane);
    if (lane < NN) {
      int pos = (int)(s & 0xFFFFFFFFull);
      int base = (b * GG + g0 + w) * NN + lane;
      out[base] = kidx[w][pos];           // pred_idx
      out[BB * GG * NN + base] = g0 + w;  // gt_idx
    }
  }
}

extern "C" void kernel_launch(void* const* d_in, const int* in_sizes, int n_in,
                              void* d_out, int out_size, void* d_ws, size_t ws_size,
                              hipStream_t stream) {
  (void)in_sizes;
  (void)n_in;
  (void)out_size;
  (void)d_ws;
  (void)ws_size;
  const float4* pred = (const float4*)d_in[0];  // [B, Q, 4] f32
  const float4* gt = (const float4*)d_in[1];    // [B, G, 4] f32
  int* out = (int*)d_out;                       // [2 * B * G * N] int32
  atss_kernel<<<(GG / TT) * BB, TH, 0, stream>>>(pred, gt, out);
}